// Round 1
// baseline (798.407 us; speedup 1.0000x reference)
//
#include <hip/hip_runtime.h>
#include <hip/hip_bf16.h>

// Problem constants (fixed by reference)
#define D_MODEL 256
#define NHEAD   8
#define NLEV    4
#define NPTS    4
#define HDIM    32
#define DFFN    512
#define NBATCH  8
#define LQ      1000
#define LIN     21760            // 128*128 + 64*64 + 32*32 + 16*16
#define M_VAL   (NBATCH * LIN)   // 174080
#define M_Q     (NBATCH * LQ)    // 8000

struct alignas(8) bf16x4 { __hip_bfloat16 a, b, c, d; };

// ---------------------------------------------------------------------------
// Generic tiled f32 GEMM: C[M,N] = op(A [+ A2]) @ B + bias, optional ReLU,
// optional row mask (zero row), optional bf16 output.
// Requires M % 64 == 0, N % 64 == 0, K % 16 == 0 (true for all our shapes).
// Block: 256 threads; tile 64x64; each thread computes 4x4.
// ---------------------------------------------------------------------------
template<bool ADD_A2, bool RELU, bool MASK, bool OUT_BF16>
__global__ __launch_bounds__(256)
void gemm_kernel(const float* __restrict__ A, const float* __restrict__ A2,
                 const float* __restrict__ B, const float* __restrict__ bias,
                 const unsigned char* __restrict__ mask,
                 float* __restrict__ C, __hip_bfloat16* __restrict__ Cb,
                 int M, int N, int K)
{
    __shared__ float As[16][68];   // transposed A tile [k][m], padded row
    __shared__ float Bs[16][64];   // B tile [k][n]

    const int tid = threadIdx.x;
    const long bm = (long)blockIdx.y * 64;
    const int  bn = blockIdx.x * 64;
    const int  tx = tid & 15;        // output col group
    const int  ty = tid >> 4;        // output row group
    const int  ar = tid >> 2;        // A-load row within tile (0..63)
    const int  ac = (tid & 3) * 4;   // A-load k offset (0,4,8,12)

    float acc[4][4] = {};

    const float* Aptr  = A + (bm + ar) * (long)K + ac;
    const float* A2ptr = ADD_A2 ? (A2 + (bm + ar) * (long)K + ac) : nullptr;
    const float* Bptr  = B + (long)ty * N + bn + tx * 4;

    for (int k0 = 0; k0 < K; k0 += 16) {
        float4 av = *reinterpret_cast<const float4*>(Aptr + k0);
        if (ADD_A2) {
            float4 a2 = *reinterpret_cast<const float4*>(A2ptr + k0);
            av.x += a2.x; av.y += a2.y; av.z += a2.z; av.w += a2.w;
        }
        float4 bv = *reinterpret_cast<const float4*>(Bptr + (long)k0 * N);

        As[ac + 0][ar] = av.x;
        As[ac + 1][ar] = av.y;
        As[ac + 2][ar] = av.z;
        As[ac + 3][ar] = av.w;
        *reinterpret_cast<float4*>(&Bs[ty][tx * 4]) = bv;
        __syncthreads();

        #pragma unroll
        for (int kk = 0; kk < 16; ++kk) {
            float4 a4 = *reinterpret_cast<const float4*>(&As[kk][ty * 4]);
            float4 b4 = *reinterpret_cast<const float4*>(&Bs[kk][tx * 4]);
            float a[4] = {a4.x, a4.y, a4.z, a4.w};
            float b[4] = {b4.x, b4.y, b4.z, b4.w};
            #pragma unroll
            for (int i = 0; i < 4; ++i)
                #pragma unroll
                for (int j = 0; j < 4; ++j)
                    acc[i][j] = fmaf(a[i], b[j], acc[i][j]);
        }
        __syncthreads();
    }

    const float4 bias4 = *reinterpret_cast<const float4*>(bias + bn + tx * 4);

    #pragma unroll
    for (int i = 0; i < 4; ++i) {
        const long row = bm + ty * 4 + i;
        float o0 = acc[i][0] + bias4.x;
        float o1 = acc[i][1] + bias4.y;
        float o2 = acc[i][2] + bias4.z;
        float o3 = acc[i][3] + bias4.w;
        if (RELU) {
            o0 = fmaxf(o0, 0.f); o1 = fmaxf(o1, 0.f);
            o2 = fmaxf(o2, 0.f); o3 = fmaxf(o3, 0.f);
        }
        if (MASK) {
            if (mask[row]) { o0 = o1 = o2 = o3 = 0.f; }
        }
        const long off = row * N + bn + tx * 4;
        if (OUT_BF16) {
            bf16x4 v { __float2bfloat16(o0), __float2bfloat16(o1),
                       __float2bfloat16(o2), __float2bfloat16(o3) };
            *reinterpret_cast<bf16x4*>(Cb + off) = v;
        } else {
            *reinterpret_cast<float4*>(C + off) = make_float4(o0, o1, o2, o3);
        }
    }
}

// ---------------------------------------------------------------------------
// Fused softmax + multi-scale deformable sampling.
// One block per query (8000 blocks). 256 threads = 8 heads x 32 channels.
// Each 32-lane channel group does coalesced 64B gathers from bf16 value.
// ---------------------------------------------------------------------------
__global__ __launch_bounds__(256)
void msdeform_sample_kernel(const float* __restrict__ off,
                            const float* __restrict__ logits,
                            const float* __restrict__ ref_pts,
                            const __hip_bfloat16* __restrict__ value,
                            float* __restrict__ samp)
{
    const int qi = blockIdx.x;           // 0..7999 (= n*1000 + lq)
    const int n  = qi / LQ;
    const int t  = threadIdx.x;
    const int h  = t >> 5;
    const int c  = t & 31;

    // per-(query,head) softmax over L*P=16 logits (redundant across 32 lanes,
    // all reads L1-broadcast; ~16 expf per thread)
    const float* lrow = logits + (long)qi * (NHEAD * 16) + h * 16;
    float lg[16];
    float mx = -1e30f;
    #pragma unroll
    for (int i = 0; i < 16; ++i) { lg[i] = lrow[i]; mx = fmaxf(mx, lg[i]); }
    float s = 0.f;
    #pragma unroll
    for (int i = 0; i < 16; ++i) { lg[i] = expf(lg[i] - mx); s += lg[i]; }
    const float inv = 1.f / s;

    constexpr int HLvl[4]  = {128, 64, 32, 16};
    constexpr int WLvl[4]  = {128, 64, 32, 16};
    constexpr int Start[4] = {0, 16384, 20480, 21504};

    const float* offrow = off + (long)qi * 256 + h * 32;  // [L][P][2] per head
    const float* refrow = ref_pts + (long)qi * 8;         // [L][2]

    float acc = 0.f;
    #pragma unroll
    for (int l = 0; l < NLEV; ++l) {
        const int Hl = HLvl[l], Wl = WLvl[l], st = Start[l];
        // x = (ref_x + off_x / Wl) * Wl - 0.5 = ref_x*Wl + off_x - 0.5
        const float rx = refrow[l * 2 + 0] * (float)Wl - 0.5f;
        const float ry = refrow[l * 2 + 1] * (float)Hl - 0.5f;
        const long  base = (long)n * LIN + st;
        #pragma unroll
        for (int p = 0; p < NPTS; ++p) {
            const float x = rx + offrow[(l * 4 + p) * 2 + 0];
            const float y = ry + offrow[(l * 4 + p) * 2 + 1];
            const float x0f = floorf(x), y0f = floorf(y);
            const float fx = x - x0f, fy = y - y0f;
            const int x0 = (int)x0f, y0 = (int)y0f;
            const float w = lg[l * 4 + p] * inv;
            float sv = 0.f;
            #pragma unroll
            for (int dy = 0; dy < 2; ++dy) {
                const int yi = y0 + dy;
                if ((unsigned)yi >= (unsigned)Hl) continue;
                const float wy = dy ? fy : 1.f - fy;
                #pragma unroll
                for (int dx = 0; dx < 2; ++dx) {
                    const int xi = x0 + dx;
                    if ((unsigned)xi >= (unsigned)Wl) continue;
                    const float wx = dx ? fx : 1.f - fx;
                    const long vidx = ((base + (long)yi * Wl + xi) * NHEAD + h) * HDIM + c;
                    sv = fmaf(wx * wy, __bfloat162float(value[vidx]), sv);
                }
            }
            acc = fmaf(w, sv, acc);
        }
    }
    samp[(long)qi * D_MODEL + h * HDIM + c] = acc;
}

// ---------------------------------------------------------------------------
// Fused residual-add + LayerNorm over D=256. One wave (64 lanes) per row,
// 4 floats per lane; 4 rows per 256-thread block.
// ---------------------------------------------------------------------------
__global__ __launch_bounds__(256)
void add_ln_kernel(const float* __restrict__ x, const float* __restrict__ y,
                   const float* __restrict__ g, const float* __restrict__ b,
                   float* __restrict__ out)
{
    const int row  = blockIdx.x * 4 + (threadIdx.x >> 6);
    const int lane = threadIdx.x & 63;
    const long base = (long)row * D_MODEL + lane * 4;

    float4 xv = *reinterpret_cast<const float4*>(x + base);
    float4 yv = *reinterpret_cast<const float4*>(y + base);
    float4 v  = make_float4(xv.x + yv.x, xv.y + yv.y, xv.z + yv.z, xv.w + yv.w);

    float sum = v.x + v.y + v.z + v.w;
    float sq  = v.x * v.x + v.y * v.y + v.z * v.z + v.w * v.w;
    #pragma unroll
    for (int m = 1; m < 64; m <<= 1) {
        sum += __shfl_xor(sum, m, 64);
        sq  += __shfl_xor(sq,  m, 64);
    }
    const float mean = sum * (1.f / D_MODEL);
    const float var  = sq * (1.f / D_MODEL) - mean * mean;
    const float rstd = rsqrtf(var + 1e-5f);

    float4 gv = *reinterpret_cast<const float4*>(g + lane * 4);
    float4 bv = *reinterpret_cast<const float4*>(b + lane * 4);
    float4 o;
    o.x = (v.x - mean) * rstd * gv.x + bv.x;
    o.y = (v.y - mean) * rstd * gv.y + bv.y;
    o.z = (v.z - mean) * rstd * gv.z + bv.z;
    o.w = (v.w - mean) * rstd * gv.w + bv.w;
    *reinterpret_cast<float4*>(out + base) = o;
}

// ---------------------------------------------------------------------------
extern "C" void kernel_launch(void* const* d_in, const int* in_sizes, int n_in,
                              void* d_out, int out_size, void* d_ws, size_t ws_size,
                              hipStream_t stream)
{
    const float* pre_tgt  = (const float*)d_in[0];
    const float* pre_qpos = (const float*)d_in[1];
    const float* src      = (const float*)d_in[2];
    const float* ref_pts  = (const float*)d_in[3];
    const unsigned char* pad_mask = (const unsigned char*)d_in[4];
    // d_in[5]=src_spatial_shapes, d_in[6]=level_start_index: compile-time consts
    const float* W_value = (const float*)d_in[7];
    const float* b_value = (const float*)d_in[8];
    const float* W_off   = (const float*)d_in[9];
    const float* b_off   = (const float*)d_in[10];
    const float* W_attn  = (const float*)d_in[11];
    const float* b_attn  = (const float*)d_in[12];
    const float* W_out   = (const float*)d_in[13];
    const float* b_out   = (const float*)d_in[14];
    const float* g1      = (const float*)d_in[15];
    const float* be1     = (const float*)d_in[16];
    const float* W1      = (const float*)d_in[17];
    const float* b1      = (const float*)d_in[18];
    const float* W2      = (const float*)d_in[19];
    const float* b2      = (const float*)d_in[20];
    const float* g3      = (const float*)d_in[21];
    const float* be3     = (const float*)d_in[22];
    float* out = (float*)d_out;

    // Workspace layout (≈118 MB total)
    char* w = (char*)d_ws;
    __hip_bfloat16* value = (__hip_bfloat16*)w;               // 174080*256*2 B
    size_t o = (size_t)M_VAL * D_MODEL * 2;
    float* offb   = (float*)(w + o); o += (size_t)M_Q * 256 * 4;
    float* logits = (float*)(w + o); o += (size_t)M_Q * 128 * 4;
    float* samp   = (float*)(w + o); o += (size_t)M_Q * 256 * 4;
    float* tgt    = (float*)(w + o); o += (size_t)M_Q * 256 * 4;
    // Aliases over dead buffers:
    float* hidden   = (float*)d_ws; // over value region (value dead after sampling)
    float* attn_out = offb;         // off dead after sampling
    float* ff       = samp;         // samp dead after out-proj

    const dim3 blk(256);

    // 1. value = src @ W_value + b_value, masked, stored bf16
    gemm_kernel<false, false, true, true><<<dim3(4, M_VAL / 64), blk, 0, stream>>>(
        src, nullptr, W_value, b_value, pad_mask, nullptr, value, M_VAL, 256, 256);

    // 2. off = (pre_tgt + pre_query_pos) @ W_off + b_off
    gemm_kernel<true, false, false, false><<<dim3(4, M_Q / 64), blk, 0, stream>>>(
        pre_tgt, pre_qpos, W_off, b_off, nullptr, offb, nullptr, M_Q, 256, 256);

    // 3. attn logits = (pre_tgt + pre_query_pos) @ W_attn + b_attn
    gemm_kernel<true, false, false, false><<<dim3(2, M_Q / 64), blk, 0, stream>>>(
        pre_tgt, pre_qpos, W_attn, b_attn, nullptr, logits, nullptr, M_Q, 128, 256);

    // 4. fused softmax + bilinear sampling -> samp [8000, 256]
    msdeform_sample_kernel<<<dim3(M_Q), blk, 0, stream>>>(offb, logits, ref_pts, value, samp);

    // 5. attn_out = samp @ W_out + b_out
    gemm_kernel<false, false, false, false><<<dim3(4, M_Q / 64), blk, 0, stream>>>(
        samp, nullptr, W_out, b_out, nullptr, attn_out, nullptr, M_Q, 256, 256);

    // 6. tgt = LN(pre_tgt + attn_out)
    add_ln_kernel<<<dim3(M_Q / 4), blk, 0, stream>>>(pre_tgt, attn_out, g1, be1, tgt);

    // 7. hidden = relu(tgt @ W1 + b1)
    gemm_kernel<false, true, false, false><<<dim3(8, M_Q / 64), blk, 0, stream>>>(
        tgt, nullptr, W1, b1, nullptr, hidden, nullptr, M_Q, 512, 256);

    // 8. ff = hidden @ W2 + b2
    gemm_kernel<false, false, false, false><<<dim3(4, M_Q / 64), blk, 0, stream>>>(
        hidden, nullptr, W2, b2, nullptr, ff, nullptr, M_Q, 256, 512);

    // 9. out = LN(tgt + ff)
    add_ln_kernel<<<dim3(M_Q / 4), blk, 0, stream>>>(tgt, ff, g3, be3, out);
}

// Round 2
// 434.362 us; speedup vs baseline: 1.8381x; 1.8381x over previous
//
#include <hip/hip_runtime.h>
#include <hip/hip_bf16.h>

// Problem constants (fixed by reference)
#define D_MODEL 256
#define NHEAD   8
#define NLEV    4
#define NPTS    4
#define HDIM    32
#define DFFN    512
#define NBATCH  8
#define LQ      1000
#define LIN     21760            // 128*128 + 64*64 + 32*32 + 16*16
#define M_VAL   (NBATCH * LIN)   // 174080
#define M_Q     (NBATCH * LQ)    // 8000

typedef __attribute__((ext_vector_type(8))) short short8;
typedef __attribute__((ext_vector_type(4))) short short4v;
typedef __attribute__((ext_vector_type(4))) float f32x4;

struct alignas(8) bf16x4 { __hip_bfloat16 a, b, c, d; };

__device__ __forceinline__ short f2bf(float f) {
    __hip_bfloat16 h = __float2bfloat16(f);
    return *reinterpret_cast<short*>(&h);
}

// ---------------------------------------------------------------------------
// Weight prep: transpose f32 [K][N] -> bf16 [N][K] for MFMA B-operand.
// Tiles of 32x32; block = 256 threads (32x8).
// Tile ranges: W_value 64 | W_out 64 | W1 (256x512) 128 | W2 (512x256) 128
// ---------------------------------------------------------------------------
__global__ __launch_bounds__(256)
void transpose_weights_kernel(const float* __restrict__ Wv, const float* __restrict__ Wo,
                              const float* __restrict__ W1, const float* __restrict__ W2,
                              short* __restrict__ Wv_t, short* __restrict__ Wo_t,
                              short* __restrict__ W1_t, short* __restrict__ W2_t)
{
    const int b = blockIdx.x;
    const float* src; short* dst; int K, N, tb;
    if (b < 64)       { src = Wv; dst = Wv_t; K = 256; N = 256; tb = b; }
    else if (b < 128) { src = Wo; dst = Wo_t; K = 256; N = 256; tb = b - 64; }
    else if (b < 256) { src = W1; dst = W1_t; K = 256; N = 512; tb = b - 128; }
    else              { src = W2; dst = W2_t; K = 512; N = 256; tb = b - 256; }
    const int ntn = N >> 5;
    const int kt = tb / ntn, nt = tb % ntn;
    __shared__ float t[32][33];
    const int x = threadIdx.x & 31, y = threadIdx.x >> 5;
    #pragma unroll
    for (int j = 0; j < 4; ++j)
        t[y + 8*j][x] = src[(kt*32 + y + 8*j) * N + nt*32 + x];
    __syncthreads();
    #pragma unroll
    for (int j = 0; j < 4; ++j)
        dst[(nt*32 + y + 8*j) * K + kt*32 + x] = f2bf(t[x][y + 8*j]);
}

// ---------------------------------------------------------------------------
// bf16 MFMA GEMM: C[M,N] = A @ B + bias (B given transposed bf16 [N][K]).
// A either f32 [M][K] (converted during staging) or bf16 [M][K].
// BM=64 BN=128 BK=64, 256 threads = 4 waves (2x2), wave tile 32x64.
// LDS XOR-swizzle (elem ^= (row&7)<<3) for conflict-free ds_read_b128.
// Requires M%64==0, N%128==0, K%64==0.
// ---------------------------------------------------------------------------
#define BM 64
#define BN 128
#define BK 64

template<bool A_BF16, bool RELU, bool MASK, bool OUT_BF16>
__global__ __launch_bounds__(256)
void mfma_gemm_kernel(const void* __restrict__ Ain,
                      const short* __restrict__ Bt,
                      const float* __restrict__ bias,
                      const unsigned char* __restrict__ mask,
                      float* __restrict__ C, __hip_bfloat16* __restrict__ Cb,
                      int M, int N, int K)
{
    __shared__ short As[BM * BK];
    __shared__ short Bs[BN * BK];
    const int tid  = threadIdx.x;
    const int lane = tid & 63, wid = tid >> 6;
    const int wr = wid >> 1, wc = wid & 1;
    const long bm = (long)blockIdx.y * BM;
    const int  bn = blockIdx.x * BN;

    f32x4 acc[2][4];
    #pragma unroll
    for (int m = 0; m < 2; ++m)
        #pragma unroll
        for (int n = 0; n < 4; ++n)
            acc[m][n] = (f32x4){0.f, 0.f, 0.f, 0.f};

    const int ar  = tid >> 2;          // A stage row 0..63
    const int akq = (tid & 3) * 16;    // A stage k offset
    const int brn = tid >> 1;          // B stage row 0..127
    const int bkq = (tid & 1) * 32;    // B stage k offset

    for (int k0 = 0; k0 < K; k0 += BK) {
        if (!A_BF16) {
            const float* Ap = (const float*)Ain + (bm + ar) * (long)K + k0 + akq;
            #pragma unroll
            for (int i = 0; i < 4; ++i) {
                float4 v = *reinterpret_cast<const float4*>(Ap + 4*i);
                short4v s;
                s[0] = f2bf(v.x); s[1] = f2bf(v.y); s[2] = f2bf(v.z); s[3] = f2bf(v.w);
                const int e = (akq + 4*i) ^ ((ar & 7) << 3);
                *reinterpret_cast<short4v*>(&As[ar * BK + e]) = s;
            }
        } else {
            const short* Ap = (const short*)Ain + (bm + ar) * (long)K + k0 + akq;
            #pragma unroll
            for (int i = 0; i < 2; ++i) {
                short8 v = *reinterpret_cast<const short8*>(Ap + 8*i);
                const int e = (akq + 8*i) ^ ((ar & 7) << 3);
                *reinterpret_cast<short8*>(&As[ar * BK + e]) = v;
            }
        }
        {
            const short* Bp = Bt + (bn + brn) * (long)K + k0 + bkq;
            #pragma unroll
            for (int i = 0; i < 4; ++i) {
                short8 v = *reinterpret_cast<const short8*>(Bp + 8*i);
                const int e = (bkq + 8*i) ^ ((brn & 7) << 3);
                *reinterpret_cast<short8*>(&Bs[brn * BK + e]) = v;
            }
        }
        __syncthreads();
        #pragma unroll
        for (int kk = 0; kk < 2; ++kk) {
            const int kb = kk * 32 + (lane >> 4) * 8;  // elem k-base for this lane
            short8 af[2], bfr[4];
            #pragma unroll
            for (int m = 0; m < 2; ++m) {
                const int row = wr * 32 + m * 16 + (lane & 15);
                af[m] = *reinterpret_cast<const short8*>(&As[row * BK + (kb ^ ((row & 7) << 3))]);
            }
            #pragma unroll
            for (int n = 0; n < 4; ++n) {
                const int row = wc * 64 + n * 16 + (lane & 15);
                bfr[n] = *reinterpret_cast<const short8*>(&Bs[row * BK + (kb ^ ((row & 7) << 3))]);
            }
            #pragma unroll
            for (int m = 0; m < 2; ++m)
                #pragma unroll
                for (int n = 0; n < 4; ++n)
                    acc[m][n] = __builtin_amdgcn_mfma_f32_16x16x32_bf16(af[m], bfr[n], acc[m][n], 0, 0, 0);
        }
        __syncthreads();
    }

    // Epilogue. C/D layout: col = lane&15, row = (lane>>4)*4 + r  [m89/m91]
    #pragma unroll
    for (int m = 0; m < 2; ++m) {
        #pragma unroll
        for (int n = 0; n < 4; ++n) {
            const int col = bn + wc * 64 + n * 16 + (lane & 15);
            const float bc = bias[col];
            #pragma unroll
            for (int r = 0; r < 4; ++r) {
                const long row = bm + wr * 32 + m * 16 + (lane >> 4) * 4 + r;
                float v = acc[m][n][r] + bc;
                if (RELU) v = fmaxf(v, 0.f);
                if (MASK) { if (mask[row]) v = 0.f; }
                if (OUT_BF16) Cb[row * (long)N + col] = __float2bfloat16(v);
                else          C[row * (long)N + col]  = v;
            }
        }
    }
}

// ---------------------------------------------------------------------------
// f32 SIMT GEMM kept for the small precision-sensitive projections (off, attn).
// ---------------------------------------------------------------------------
template<bool ADD_A2>
__global__ __launch_bounds__(256)
void gemm_kernel(const float* __restrict__ A, const float* __restrict__ A2,
                 const float* __restrict__ B, const float* __restrict__ bias,
                 float* __restrict__ C, int M, int N, int K)
{
    __shared__ float As[16][68];
    __shared__ float Bs[16][64];
    const int tid = threadIdx.x;
    const long bm = (long)blockIdx.y * 64;
    const int  bn = blockIdx.x * 64;
    const int  tx = tid & 15, ty = tid >> 4;
    const int  ar = tid >> 2, ac = (tid & 3) * 4;

    float acc[4][4] = {};
    const float* Aptr  = A + (bm + ar) * (long)K + ac;
    const float* A2ptr = ADD_A2 ? (A2 + (bm + ar) * (long)K + ac) : nullptr;
    const float* Bptr  = B + (long)ty * N + bn + tx * 4;

    for (int k0 = 0; k0 < K; k0 += 16) {
        float4 av = *reinterpret_cast<const float4*>(Aptr + k0);
        if (ADD_A2) {
            float4 a2 = *reinterpret_cast<const float4*>(A2ptr + k0);
            av.x += a2.x; av.y += a2.y; av.z += a2.z; av.w += a2.w;
        }
        float4 bv = *reinterpret_cast<const float4*>(Bptr + (long)k0 * N);
        As[ac + 0][ar] = av.x; As[ac + 1][ar] = av.y;
        As[ac + 2][ar] = av.z; As[ac + 3][ar] = av.w;
        *reinterpret_cast<float4*>(&Bs[ty][tx * 4]) = bv;
        __syncthreads();
        #pragma unroll
        for (int kk = 0; kk < 16; ++kk) {
            float4 a4 = *reinterpret_cast<const float4*>(&As[kk][ty * 4]);
            float4 b4 = *reinterpret_cast<const float4*>(&Bs[kk][tx * 4]);
            float a[4] = {a4.x, a4.y, a4.z, a4.w};
            float b[4] = {b4.x, b4.y, b4.z, b4.w};
            #pragma unroll
            for (int i = 0; i < 4; ++i)
                #pragma unroll
                for (int j = 0; j < 4; ++j)
                    acc[i][j] = fmaf(a[i], b[j], acc[i][j]);
        }
        __syncthreads();
    }
    const float4 bias4 = *reinterpret_cast<const float4*>(bias + bn + tx * 4);
    #pragma unroll
    for (int i = 0; i < 4; ++i) {
        const long row = bm + ty * 4 + i;
        const long off = row * N + bn + tx * 4;
        *reinterpret_cast<float4*>(C + off) = make_float4(
            acc[i][0] + bias4.x, acc[i][1] + bias4.y,
            acc[i][2] + bias4.z, acc[i][3] + bias4.w);
    }
}

// ---------------------------------------------------------------------------
// Fused softmax + multi-scale deformable sampling, 2-phase.
// One block per query, 128 threads.
// Phase 1: thread = (h, l*4+p): cooperative 16-lane softmax, tap indices +
//          fused weights -> LDS.  Phase 2: thread = (h, channel-pair): pure
//          gather+fma. Output samp in bf16 (feeds MFMA out-proj).
// ---------------------------------------------------------------------------
__global__ __launch_bounds__(128)
void msdeform_sample_kernel(const float* __restrict__ off,
                            const float* __restrict__ logits,
                            const float* __restrict__ ref_pts,
                            const __hip_bfloat16* __restrict__ value,
                            __hip_bfloat16* __restrict__ samp)
{
    const int qi = blockIdx.x;
    const int n  = qi / LQ;
    const int t  = threadIdx.x;

    __shared__ int   s_idx[128][4];
    __shared__ float s_w[128][4];

    {   // phase 1: t = h*16 + lp
        const int h = t >> 4, lp = t & 15, l = lp >> 2;
        const float lg = logits[qi * 128 + t];
        float mx = lg;
        #pragma unroll
        for (int m = 1; m < 16; m <<= 1) mx = fmaxf(mx, __shfl_xor(mx, m, 64));
        const float e = __expf(lg - mx);
        float s = e;
        #pragma unroll
        for (int m = 1; m < 16; m <<= 1) s += __shfl_xor(s, m, 64);
        const float w = e / s;

        const int Wl = 128 >> l;              // 128,64,32,16 (square levels)
        constexpr int Start[4] = {0, 16384, 20480, 21504};
        const float x = ref_pts[qi * 8 + l * 2 + 0] * (float)Wl - 0.5f
                      + off[qi * 256 + h * 32 + lp * 2 + 0];
        const float y = ref_pts[qi * 8 + l * 2 + 1] * (float)Wl - 0.5f
                      + off[qi * 256 + h * 32 + lp * 2 + 1];
        const float x0f = floorf(x), y0f = floorf(y);
        const float fx = x - x0f, fy = y - y0f;
        const int x0 = (int)x0f, y0 = (int)y0f;
        const int base = n * LIN + Start[l];
        #pragma unroll
        for (int tap = 0; tap < 4; ++tap) {
            const int dx = tap & 1, dy = tap >> 1;
            const int xi = x0 + dx, yi = y0 + dy;
            const bool ok = ((unsigned)xi < (unsigned)Wl) & ((unsigned)yi < (unsigned)Wl);
            const float tw = ok ? w * (dx ? fx : 1.f - fx) * (dy ? fy : 1.f - fy) : 0.f;
            const int idx = ok ? ((base + yi * Wl + xi) * D_MODEL + h * HDIM) : 0;
            s_idx[t][tap] = idx;
            s_w[t][tap]   = tw;
        }
    }
    __syncthreads();

    {   // phase 2: t = h*16 + cp  (cp = channel pair 0..15)
        const int h = t >> 4, cp = t & 15;
        float a0 = 0.f, a1 = 0.f;
        #pragma unroll
        for (int lp = 0; lp < 16; ++lp) {
            const int4   i4 = *reinterpret_cast<const int4*>(s_idx[h * 16 + lp]);
            const float4 w4 = *reinterpret_cast<const float4*>(s_w[h * 16 + lp]);
            const int   idx[4] = {i4.x, i4.y, i4.z, i4.w};
            const float wt[4]  = {w4.x, w4.y, w4.z, w4.w};
            #pragma unroll
            for (int tap = 0; tap < 4; ++tap) {
                __hip_bfloat162 v2 = *reinterpret_cast<const __hip_bfloat162*>(
                    value + idx[tap] + cp * 2);
                a0 = fmaf(wt[tap], __bfloat162float(v2.x), a0);
                a1 = fmaf(wt[tap], __bfloat162float(v2.y), a1);
            }
        }
        __hip_bfloat162 o;
        o.x = __float2bfloat16(a0);
        o.y = __float2bfloat16(a1);
        *reinterpret_cast<__hip_bfloat162*>(samp + (long)qi * D_MODEL + h * HDIM + cp * 2) = o;
    }
}

// ---------------------------------------------------------------------------
// Fused residual-add + LayerNorm over D=256. One wave per row, 4 rows/block.
// ---------------------------------------------------------------------------
__global__ __launch_bounds__(256)
void add_ln_kernel(const float* __restrict__ x, const float* __restrict__ y,
                   const float* __restrict__ g, const float* __restrict__ b,
                   float* __restrict__ out)
{
    const int row  = blockIdx.x * 4 + (threadIdx.x >> 6);
    const int lane = threadIdx.x & 63;
    const long base = (long)row * D_MODEL + lane * 4;

    float4 xv = *reinterpret_cast<const float4*>(x + base);
    float4 yv = *reinterpret_cast<const float4*>(y + base);
    float4 v  = make_float4(xv.x + yv.x, xv.y + yv.y, xv.z + yv.z, xv.w + yv.w);

    float sum = v.x + v.y + v.z + v.w;
    float sq  = v.x * v.x + v.y * v.y + v.z * v.z + v.w * v.w;
    #pragma unroll
    for (int m = 1; m < 64; m <<= 1) {
        sum += __shfl_xor(sum, m, 64);
        sq  += __shfl_xor(sq,  m, 64);
    }
    const float mean = sum * (1.f / D_MODEL);
    const float var  = sq * (1.f / D_MODEL) - mean * mean;
    const float rstd = rsqrtf(var + 1e-5f);

    float4 gv = *reinterpret_cast<const float4*>(g + lane * 4);
    float4 bv = *reinterpret_cast<const float4*>(b + lane * 4);
    float4 o;
    o.x = (v.x - mean) * rstd * gv.x + bv.x;
    o.y = (v.y - mean) * rstd * gv.y + bv.y;
    o.z = (v.z - mean) * rstd * gv.z + bv.z;
    o.w = (v.w - mean) * rstd * gv.w + bv.w;
    *reinterpret_cast<float4*>(out + base) = o;
}

// ---------------------------------------------------------------------------
extern "C" void kernel_launch(void* const* d_in, const int* in_sizes, int n_in,
                              void* d_out, int out_size, void* d_ws, size_t ws_size,
                              hipStream_t stream)
{
    const float* pre_tgt  = (const float*)d_in[0];
    const float* pre_qpos = (const float*)d_in[1];
    const float* src      = (const float*)d_in[2];
    const float* ref_pts  = (const float*)d_in[3];
    const unsigned char* pad_mask = (const unsigned char*)d_in[4];
    const float* W_value = (const float*)d_in[7];
    const float* b_value = (const float*)d_in[8];
    const float* W_off   = (const float*)d_in[9];
    const float* b_off   = (const float*)d_in[10];
    const float* W_attn  = (const float*)d_in[11];
    const float* b_attn  = (const float*)d_in[12];
    const float* W_out   = (const float*)d_in[13];
    const float* b_out   = (const float*)d_in[14];
    const float* g1      = (const float*)d_in[15];
    const float* be1     = (const float*)d_in[16];
    const float* W1      = (const float*)d_in[17];
    const float* b1      = (const float*)d_in[18];
    const float* W2      = (const float*)d_in[19];
    const float* b2      = (const float*)d_in[20];
    const float* g3      = (const float*)d_in[21];
    const float* be3     = (const float*)d_in[22];
    float* out = (float*)d_out;

    // Workspace layout (~114.5 MB; round-1 layout of 117.8 MB fit)
    char* w = (char*)d_ws;
    size_t o = 0;
    __hip_bfloat16* value = (__hip_bfloat16*)(w + o); o += (size_t)M_VAL * D_MODEL * 2;   // 89.1 MB
    float* offb    = (float*)(w + o); o += (size_t)M_Q * 256 * 4;                          // 8.2 MB
    float* logits  = (float*)(w + o); o += (size_t)M_Q * 128 * 4;                          // 4.1 MB
    __hip_bfloat16* samp = (__hip_bfloat16*)(w + o); o += (size_t)M_Q * 256 * 2;           // 4.1 MB
    float* tgt     = (float*)(w + o); o += (size_t)M_Q * 256 * 4;                          // 8.2 MB
    short* Wv_t    = (short*)(w + o); o += 256 * 256 * 2;
    short* Wo_t    = (short*)(w + o); o += 256 * 256 * 2;
    short* W1_t    = (short*)(w + o); o += 512 * 256 * 2;
    short* W2_t    = (short*)(w + o); o += 256 * 512 * 2;
    // Aliases into the (dead) value region:
    float* attn_out = (float*)w;                   // after sampling, before LN1
    float* hidden_f_unused = nullptr; (void)hidden_f_unused;
    __hip_bfloat16* hidden = (__hip_bfloat16*)(w + 20000000);  // bf16 [8000][512], after LN1
    float* ff = offb;                              // offb dead after sampling

    const dim3 blk(256);

    // 0. prep: weights -> bf16 transposed [N][K]
    transpose_weights_kernel<<<dim3(384), blk, 0, stream>>>(
        W_value, W_out, W1, W2, Wv_t, Wo_t, W1_t, W2_t);

    // 1. value = src @ W_value + b_value, masked, bf16 out (MFMA)
    mfma_gemm_kernel<false, false, true, true><<<dim3(2, M_VAL / BM), blk, 0, stream>>>(
        src, Wv_t, b_value, pad_mask, nullptr, value, M_VAL, 256, 256);

    // 2. off = (pre_tgt + pre_qpos) @ W_off + b_off   (f32, precision-sensitive)
    gemm_kernel<true><<<dim3(4, M_Q / 64), blk, 0, stream>>>(
        pre_tgt, pre_qpos, W_off, b_off, offb, M_Q, 256, 256);

    // 3. logits = (pre_tgt + pre_qpos) @ W_attn + b_attn  (f32)
    gemm_kernel<true><<<dim3(2, M_Q / 64), blk, 0, stream>>>(
        pre_tgt, pre_qpos, W_attn, b_attn, logits, M_Q, 128, 256);

    // 4. fused softmax + bilinear sampling -> samp bf16
    msdeform_sample_kernel<<<dim3(M_Q), dim3(128), 0, stream>>>(
        offb, logits, ref_pts, value, samp);

    // 5. attn_out = samp @ W_out + b_out (MFMA, bf16 A)
    mfma_gemm_kernel<true, false, false, false><<<dim3(2, M_Q / BM), blk, 0, stream>>>(
        samp, Wo_t, b_out, nullptr, attn_out, nullptr, M_Q, 256, 256);

    // 6. tgt = LN(pre_tgt + attn_out)
    add_ln_kernel<<<dim3(M_Q / 4), blk, 0, stream>>>(pre_tgt, attn_out, g1, be1, tgt);

    // 7. hidden = relu(tgt @ W1 + b1) (MFMA, f32 A, bf16 out)
    mfma_gemm_kernel<false, true, false, true><<<dim3(4, M_Q / BM), blk, 0, stream>>>(
        tgt, W1_t, b1, nullptr, nullptr, hidden, M_Q, 512, 256);

    // 8. ff = hidden @ W2 + b2 (MFMA, bf16 A, K=512)
    mfma_gemm_kernel<true, false, false, false><<<dim3(2, M_Q / BM), blk, 0, stream>>>(
        hidden, W2_t, b2, nullptr, ff, nullptr, M_Q, 256, 512);

    // 9. out = LN(tgt + ff)
    add_ln_kernel<<<dim3(M_Q / 4), blk, 0, stream>>>(tgt, ff, g3, be3, out);
}

// Round 3
// 418.544 us; speedup vs baseline: 1.9076x; 1.0378x over previous
//
#include <hip/hip_runtime.h>
#include <hip/hip_bf16.h>

// Problem constants (fixed by reference)
#define D_MODEL 256
#define NHEAD   8
#define NLEV    4
#define NPTS    4
#define HDIM    32
#define DFFN    512
#define NBATCH  8
#define LQ      1000
#define LIN     21760            // 128*128 + 64*64 + 32*32 + 16*16
#define M_VAL   (NBATCH * LIN)   // 174080
#define M_Q     (NBATCH * LQ)    // 8000

typedef __attribute__((ext_vector_type(8))) short short8;
typedef __attribute__((ext_vector_type(4))) short short4v;
typedef __attribute__((ext_vector_type(4))) float f32x4;

struct alignas(8) bf16x4 { __hip_bfloat16 a, b, c, d; };

__device__ __forceinline__ short f2bf(float f) {
    __hip_bfloat16 h = __float2bfloat16(f);
    return *reinterpret_cast<short*>(&h);
}
__device__ __forceinline__ float bf2f(short s) {
    return __uint_as_float(((unsigned)(unsigned short)s) << 16);
}

// ---------------------------------------------------------------------------
// Weight prep: transpose f32 [K][N] -> bf16 [N][K] for MFMA B-operand.
// ---------------------------------------------------------------------------
__global__ __launch_bounds__(256)
void transpose_weights_kernel(const float* __restrict__ Wv, const float* __restrict__ Wo,
                              const float* __restrict__ W1, const float* __restrict__ W2,
                              short* __restrict__ Wv_t, short* __restrict__ Wo_t,
                              short* __restrict__ W1_t, short* __restrict__ W2_t)
{
    const int b = blockIdx.x;
    const float* src; short* dst; int K, N, tb;
    if (b < 64)       { src = Wv; dst = Wv_t; K = 256; N = 256; tb = b; }
    else if (b < 128) { src = Wo; dst = Wo_t; K = 256; N = 256; tb = b - 64; }
    else if (b < 256) { src = W1; dst = W1_t; K = 256; N = 512; tb = b - 128; }
    else              { src = W2; dst = W2_t; K = 512; N = 256; tb = b - 256; }
    const int ntn = N >> 5;
    const int kt = tb / ntn, nt = tb % ntn;
    __shared__ float t[32][33];
    const int x = threadIdx.x & 31, y = threadIdx.x >> 5;
    #pragma unroll
    for (int j = 0; j < 4; ++j)
        t[y + 8*j][x] = src[(kt*32 + y + 8*j) * N + nt*32 + x];
    __syncthreads();
    #pragma unroll
    for (int j = 0; j < 4; ++j)
        dst[(nt*32 + y + 8*j) * K + kt*32 + x] = f2bf(t[x][y + 8*j]);
}

// ---------------------------------------------------------------------------
// bf16 MFMA GEMM, 2-phase pipelined (prefetch next tile regs before compute).
// OMODE: 0 = f32 row-major, 1 = bf16 row-major, 2 = bf16 head-planes
//        (plane layout: addr = (col>>5)*M_VAL*32 + row*32 + (col&31))
// BM=64 BN=128 BK=64, 256 threads = 4 waves (2x2), wave tile 32x64.
// ---------------------------------------------------------------------------
#define BM 64
#define BN 128
#define BK 64

template<bool A_BF16, bool RELU, bool MASK, int OMODE>
__global__ __launch_bounds__(256)
void mfma_gemm_kernel(const void* __restrict__ Ain,
                      const short* __restrict__ Bt,
                      const float* __restrict__ bias,
                      const unsigned char* __restrict__ mask,
                      float* __restrict__ C, __hip_bfloat16* __restrict__ Cb,
                      int M, int N, int K)
{
    __shared__ short As[BM * BK];
    __shared__ short Bs[BN * BK];
    const int tid  = threadIdx.x;
    const int lane = tid & 63, wid = tid >> 6;
    const int wr = wid >> 1, wc = wid & 1;
    const long bm = (long)blockIdx.y * BM;
    const int  bn = blockIdx.x * BN;

    f32x4 acc[2][4];
    #pragma unroll
    for (int m = 0; m < 2; ++m)
        #pragma unroll
        for (int n = 0; n < 4; ++n)
            acc[m][n] = (f32x4){0.f, 0.f, 0.f, 0.f};

    const int ar  = tid >> 2;          // A stage row 0..63
    const int akq = (tid & 3) * 16;    // A stage k offset
    const int brn = tid >> 1;          // B stage row 0..127
    const int bkq = (tid & 1) * 32;    // B stage k offset

    float4 a_f[4];
    short8 a_h[2];
    short8 b_r[4];

    auto load_tile = [&](int k0) {
        if (!A_BF16) {
            const float* Ap = (const float*)Ain + (bm + ar) * (long)K + k0 + akq;
            #pragma unroll
            for (int i = 0; i < 4; ++i)
                a_f[i] = *reinterpret_cast<const float4*>(Ap + 4*i);
        } else {
            const short* Ap = (const short*)Ain + (bm + ar) * (long)K + k0 + akq;
            #pragma unroll
            for (int i = 0; i < 2; ++i)
                a_h[i] = *reinterpret_cast<const short8*>(Ap + 8*i);
        }
        const short* Bp = Bt + (bn + brn) * (long)K + k0 + bkq;
        #pragma unroll
        for (int i = 0; i < 4; ++i)
            b_r[i] = *reinterpret_cast<const short8*>(Bp + 8*i);
    };
    auto store_tile = [&]() {
        if (!A_BF16) {
            #pragma unroll
            for (int i = 0; i < 4; ++i) {
                short4v s;
                s[0] = f2bf(a_f[i].x); s[1] = f2bf(a_f[i].y);
                s[2] = f2bf(a_f[i].z); s[3] = f2bf(a_f[i].w);
                *reinterpret_cast<short4v*>(&As[ar * BK + ((akq + 4*i) ^ ((ar & 7) << 3))]) = s;
            }
        } else {
            #pragma unroll
            for (int i = 0; i < 2; ++i)
                *reinterpret_cast<short8*>(&As[ar * BK + ((akq + 8*i) ^ ((ar & 7) << 3))]) = a_h[i];
        }
        #pragma unroll
        for (int i = 0; i < 4; ++i)
            *reinterpret_cast<short8*>(&Bs[brn * BK + ((bkq + 8*i) ^ ((brn & 7) << 3))]) = b_r[i];
    };

    load_tile(0);
    const int nsteps = K / BK;
    for (int s = 0; s < nsteps; ++s) {
        store_tile();
        __syncthreads();
        if (s + 1 < nsteps) load_tile((s + 1) * BK);   // in flight during compute
        #pragma unroll
        for (int kk = 0; kk < 2; ++kk) {
            const int kb = kk * 32 + (lane >> 4) * 8;
            short8 af[2], bfr[4];
            #pragma unroll
            for (int m = 0; m < 2; ++m) {
                const int row = wr * 32 + m * 16 + (lane & 15);
                af[m] = *reinterpret_cast<const short8*>(&As[row * BK + (kb ^ ((row & 7) << 3))]);
            }
            #pragma unroll
            for (int n = 0; n < 4; ++n) {
                const int row = wc * 64 + n * 16 + (lane & 15);
                bfr[n] = *reinterpret_cast<const short8*>(&Bs[row * BK + (kb ^ ((row & 7) << 3))]);
            }
            #pragma unroll
            for (int m = 0; m < 2; ++m)
                #pragma unroll
                for (int n = 0; n < 4; ++n)
                    acc[m][n] = __builtin_amdgcn_mfma_f32_16x16x32_bf16(af[m], bfr[n], acc[m][n], 0, 0, 0);
        }
        __syncthreads();
    }

    // Epilogue. C/D layout: col = lane&15, row = (lane>>4)*4 + r
    #pragma unroll
    for (int m = 0; m < 2; ++m) {
        #pragma unroll
        for (int n = 0; n < 4; ++n) {
            const int col = bn + wc * 64 + n * 16 + (lane & 15);
            const float bc = bias[col];
            #pragma unroll
            for (int r = 0; r < 4; ++r) {
                const long row = bm + wr * 32 + m * 16 + (lane >> 4) * 4 + r;
                float v = acc[m][n][r] + bc;
                if (RELU) v = fmaxf(v, 0.f);
                if (MASK) { if (mask[row]) v = 0.f; }
                if (OMODE == 0)      C[row * (long)N + col] = v;
                else if (OMODE == 1) Cb[row * (long)N + col] = __float2bfloat16(v);
                else {  // head-plane bf16: [h][row][c]
                    Cb[(size_t)(col >> 5) * ((size_t)M_VAL * HDIM)
                       + (size_t)row * HDIM + (col & 31)] = __float2bfloat16(v);
                }
            }
        }
    }
}

// ---------------------------------------------------------------------------
// Fused off+attn projection, f32 SIMT (precision-sensitive), 2-phase prefetch.
// A = pre_tgt + pre_qpos [8000][256]. Grid (6,125): bn<256 -> off, else attn.
// ---------------------------------------------------------------------------
__global__ __launch_bounds__(256)
void proj_gemm_kernel(const float* __restrict__ A, const float* __restrict__ A2,
                      const float* __restrict__ Wo, const float* __restrict__ bo,
                      const float* __restrict__ Wa, const float* __restrict__ ba,
                      float* __restrict__ Co, float* __restrict__ Ca)
{
    __shared__ float As[16][68];
    __shared__ float Bs[16][64];
    const int tid = threadIdx.x;
    const long bm = (long)blockIdx.y * 64;
    const int  bn = blockIdx.x * 64;
    const float* B; const float* bias; float* C; int Nc, cb;
    if (bn < 256) { B = Wo; bias = bo; C = Co; Nc = 256; cb = bn; }
    else          { B = Wa; bias = ba; C = Ca; Nc = 128; cb = bn - 256; }

    const int tx = tid & 15, ty = tid >> 4;
    const int ar = tid >> 2, ac = (tid & 3) * 4;
    float acc[4][4] = {};
    const float* Aptr = A  + (bm + ar) * 256L + ac;
    const float* A2p  = A2 + (bm + ar) * 256L + ac;
    const float* Bptr = B + (long)ty * Nc + cb + tx * 4;

    float4 av, a2, bv;
    auto load = [&](int k0) {
        av = *reinterpret_cast<const float4*>(Aptr + k0);
        a2 = *reinterpret_cast<const float4*>(A2p + k0);
        bv = *reinterpret_cast<const float4*>(Bptr + (long)k0 * Nc);
    };
    load(0);
    for (int k0 = 0; k0 < 256; k0 += 16) {
        As[ac + 0][ar] = av.x + a2.x;
        As[ac + 1][ar] = av.y + a2.y;
        As[ac + 2][ar] = av.z + a2.z;
        As[ac + 3][ar] = av.w + a2.w;
        *reinterpret_cast<float4*>(&Bs[ty][tx * 4]) = bv;
        __syncthreads();
        if (k0 + 16 < 256) load(k0 + 16);
        #pragma unroll
        for (int kk = 0; kk < 16; ++kk) {
            float4 a4 = *reinterpret_cast<const float4*>(&As[kk][ty * 4]);
            float4 b4 = *reinterpret_cast<const float4*>(&Bs[kk][tx * 4]);
            float a[4] = {a4.x, a4.y, a4.z, a4.w};
            float b[4] = {b4.x, b4.y, b4.z, b4.w};
            #pragma unroll
            for (int i = 0; i < 4; ++i)
                #pragma unroll
                for (int j = 0; j < 4; ++j)
                    acc[i][j] = fmaf(a[i], b[j], acc[i][j]);
        }
        __syncthreads();
    }
    const float4 bias4 = *reinterpret_cast<const float4*>(bias + cb + tx * 4);
    #pragma unroll
    for (int i = 0; i < 4; ++i) {
        const long row = bm + ty * 4 + i;
        *reinterpret_cast<float4*>(C + row * Nc + cb + tx * 4) = make_float4(
            acc[i][0] + bias4.x, acc[i][1] + bias4.y,
            acc[i][2] + bias4.z, acc[i][3] + bias4.w);
    }
}

// ---------------------------------------------------------------------------
// Fused softmax + multi-scale deformable sampling, v3.
// Block = 1 query, 128 threads.
// Phase 1 (t = h*16 + lp): softmax + clamped tap-pair bases & weights -> LDS.
// Phase 2 (t = h*16 + cp): cp<8 accumulates x0-side, cp>=8 x1-side, 8B bf16x4
//   loads from head-plane value layout; single shfl_xor(8) combine at end.
// ---------------------------------------------------------------------------
__global__ __launch_bounds__(128)
void msdeform_sample_kernel(const float* __restrict__ off,
                            const float* __restrict__ logits,
                            const float* __restrict__ ref_pts,
                            const __hip_bfloat16* __restrict__ value,
                            __hip_bfloat16* __restrict__ samp)
{
    const int qi = blockIdx.x;
    const int n  = qi / LQ;
    const int t  = threadIdx.x;

    __shared__ int   s_base[128];
    __shared__ float s_wx[128][2];
    __shared__ float s_wy[128][2];

    {   // phase 1
        const int h = t >> 4, lp = t & 15, l = lp >> 2;
        const float lg = logits[qi * 128 + t];
        float mx = lg;
        #pragma unroll
        for (int m = 1; m < 16; m <<= 1) mx = fmaxf(mx, __shfl_xor(mx, m, 64));
        const float e = __expf(lg - mx);
        float ssum = e;
        #pragma unroll
        for (int m = 1; m < 16; m <<= 1) ssum += __shfl_xor(ssum, m, 64);
        const float w = e / ssum;

        const int Wl = 128 >> l;       // square levels: 128,64,32,16
        constexpr int Start[4] = {0, 16384, 20480, 21504};
        const float x = ref_pts[qi * 8 + l * 2 + 0] * (float)Wl - 0.5f
                      + off[qi * 256 + h * 32 + lp * 2 + 0];
        const float y = ref_pts[qi * 8 + l * 2 + 1] * (float)Wl - 0.5f
                      + off[qi * 256 + h * 32 + lp * 2 + 1];
        const float xf = floorf(x), yf = floorf(y);
        const float fx = x - xf, fy = y - yf;
        const int x0 = (int)xf, y0 = (int)yf;
        const int xb = min(max(x0, 0), Wl - 2);
        const int yb = min(max(y0, 0), Wl - 2);
        // weight of clamped position p: (p==x0)*(1-fx) + (p==x0+1)*fx
        const float wx0 = (xb == x0) ? (1.f - fx) : ((xb == x0 + 1) ? fx : 0.f);
        const float wx1 = (xb + 1 == x0) ? (1.f - fx) : ((xb == x0) ? fx : 0.f);
        const float wy0 = w * ((yb == y0) ? (1.f - fy) : ((yb == y0 + 1) ? fy : 0.f));
        const float wy1 = w * ((yb + 1 == y0) ? (1.f - fy) : ((yb == y0) ? fy : 0.f));

        const int row = n * LIN + Start[l] + yb * Wl + xb;
        s_base[t]  = (h * M_VAL + row) * HDIM;
        s_wx[t][0] = wx0; s_wx[t][1] = wx1;
        s_wy[t][0] = wy0; s_wy[t][1] = wy1;
    }
    __syncthreads();

    {   // phase 2
        const int h = t >> 4, cp = t & 15;
        const int side = cp >> 3, ch4 = (cp & 7) * 4;
        float a0 = 0.f, a1 = 0.f, a2 = 0.f, a3 = 0.f;
        #pragma unroll
        for (int lp = 0; lp < 16; ++lp) {
            const int i  = h * 16 + lp;
            const int rs = (128 >> (lp >> 2)) * HDIM;   // row stride (elems)
            const int b  = s_base[i] + side * HDIM + ch4;
            const float wxs = s_wx[i][side];
            const float w0 = wxs * s_wy[i][0];
            const float w1 = wxs * s_wy[i][1];
            const short4v v0 = *reinterpret_cast<const short4v*>(value + b);
            const short4v v1 = *reinterpret_cast<const short4v*>(value + b + rs);
            a0 += w0 * bf2f(v0[0]) + w1 * bf2f(v1[0]);
            a1 += w0 * bf2f(v0[1]) + w1 * bf2f(v1[1]);
            a2 += w0 * bf2f(v0[2]) + w1 * bf2f(v1[2]);
            a3 += w0 * bf2f(v0[3]) + w1 * bf2f(v1[3]);
        }
        // combine x0/x1 sides (linear): partner lane is t^8 (same wave)
        a0 += __shfl_xor(a0, 8, 64);
        a1 += __shfl_xor(a1, 8, 64);
        a2 += __shfl_xor(a2, 8, 64);
        a3 += __shfl_xor(a3, 8, 64);
        if (side == 0) {
            bf16x4 o { __float2bfloat16(a0), __float2bfloat16(a1),
                       __float2bfloat16(a2), __float2bfloat16(a3) };
            *reinterpret_cast<bf16x4*>(samp + (long)qi * D_MODEL + h * HDIM + ch4) = o;
        }
    }
}

// ---------------------------------------------------------------------------
// Fused residual-add + LayerNorm over D=256. One wave per row, 4 rows/block.
// ---------------------------------------------------------------------------
__global__ __launch_bounds__(256)
void add_ln_kernel(const float* __restrict__ x, const float* __restrict__ y,
                   const float* __restrict__ g, const float* __restrict__ b,
                   float* __restrict__ out)
{
    const int row  = blockIdx.x * 4 + (threadIdx.x >> 6);
    const int lane = threadIdx.x & 63;
    const long base = (long)row * D_MODEL + lane * 4;

    float4 xv = *reinterpret_cast<const float4*>(x + base);
    float4 yv = *reinterpret_cast<const float4*>(y + base);
    float4 v  = make_float4(xv.x + yv.x, xv.y + yv.y, xv.z + yv.z, xv.w + yv.w);

    float sum = v.x + v.y + v.z + v.w;
    float sq  = v.x * v.x + v.y * v.y + v.z * v.z + v.w * v.w;
    #pragma unroll
    for (int m = 1; m < 64; m <<= 1) {
        sum += __shfl_xor(sum, m, 64);
        sq  += __shfl_xor(sq,  m, 64);
    }
    const float mean = sum * (1.f / D_MODEL);
    const float var  = sq * (1.f / D_MODEL) - mean * mean;
    const float rstd = rsqrtf(var + 1e-5f);

    float4 gv = *reinterpret_cast<const float4*>(g + lane * 4);
    float4 bv = *reinterpret_cast<const float4*>(b + lane * 4);
    float4 o;
    o.x = (v.x - mean) * rstd * gv.x + bv.x;
    o.y = (v.y - mean) * rstd * gv.y + bv.y;
    o.z = (v.z - mean) * rstd * gv.z + bv.z;
    o.w = (v.w - mean) * rstd * gv.w + bv.w;
    *reinterpret_cast<float4*>(out + base) = o;
}

// ---------------------------------------------------------------------------
extern "C" void kernel_launch(void* const* d_in, const int* in_sizes, int n_in,
                              void* d_out, int out_size, void* d_ws, size_t ws_size,
                              hipStream_t stream)
{
    const float* pre_tgt  = (const float*)d_in[0];
    const float* pre_qpos = (const float*)d_in[1];
    const float* src      = (const float*)d_in[2];
    const float* ref_pts  = (const float*)d_in[3];
    const unsigned char* pad_mask = (const unsigned char*)d_in[4];
    const float* W_value = (const float*)d_in[7];
    const float* b_value = (const float*)d_in[8];
    const float* W_off   = (const float*)d_in[9];
    const float* b_off   = (const float*)d_in[10];
    const float* W_attn  = (const float*)d_in[11];
    const float* b_attn  = (const float*)d_in[12];
    const float* W_out   = (const float*)d_in[13];
    const float* b_out   = (const float*)d_in[14];
    const float* g1      = (const float*)d_in[15];
    const float* be1     = (const float*)d_in[16];
    const float* W1      = (const float*)d_in[17];
    const float* b1      = (const float*)d_in[18];
    const float* W2      = (const float*)d_in[19];
    const float* b2      = (const float*)d_in[20];
    const float* g3      = (const float*)d_in[21];
    const float* be3     = (const float*)d_in[22];
    float* out = (float*)d_out;

    // Workspace layout
    char* w = (char*)d_ws;
    size_t o = 0;
    __hip_bfloat16* value = (__hip_bfloat16*)(w + o); o += (size_t)M_VAL * D_MODEL * 2;   // 89.1 MB (head planes)
    float* offb    = (float*)(w + o); o += (size_t)M_Q * 256 * 4;
    float* logits  = (float*)(w + o); o += (size_t)M_Q * 128 * 4;
    __hip_bfloat16* samp = (__hip_bfloat16*)(w + o); o += (size_t)M_Q * 256 * 2;
    float* tgt     = (float*)(w + o); o += (size_t)M_Q * 256 * 4;
    short* Wv_t    = (short*)(w + o); o += 256 * 256 * 2;
    short* Wo_t    = (short*)(w + o); o += 256 * 256 * 2;
    short* W1_t    = (short*)(w + o); o += 512 * 256 * 2;
    short* W2_t    = (short*)(w + o); o += 256 * 512 * 2;
    // Aliases into the (dead) value region:
    float* attn_out = (float*)w;                               // 8 MB
    __hip_bfloat16* hidden = (__hip_bfloat16*)(w + 20000000);  // 8.2 MB bf16 [8000][512]
    float* ff = offb;                                          // offb dead after sampling

    const dim3 blk(256);

    // 0. prep: weights -> bf16 transposed [N][K]
    transpose_weights_kernel<<<dim3(384), blk, 0, stream>>>(
        W_value, W_out, W1, W2, Wv_t, Wo_t, W1_t, W2_t);

    // 1. value = src @ W_value + b_value, masked, bf16 head-plane out (MFMA)
    mfma_gemm_kernel<false, false, true, 2><<<dim3(2, M_VAL / BM), blk, 0, stream>>>(
        src, Wv_t, b_value, pad_mask, nullptr, value, M_VAL, 256, 256);

    // 2+3. fused off/attn projections (f32)
    proj_gemm_kernel<<<dim3(6, M_Q / 64), blk, 0, stream>>>(
        pre_tgt, pre_qpos, W_off, b_off, W_attn, b_attn, offb, logits);

    // 4. fused softmax + bilinear sampling -> samp bf16
    msdeform_sample_kernel<<<dim3(M_Q), dim3(128), 0, stream>>>(
        offb, logits, ref_pts, value, samp);

    // 5. attn_out = samp @ W_out + b_out (MFMA, bf16 A)
    mfma_gemm_kernel<true, false, false, 0><<<dim3(2, M_Q / BM), blk, 0, stream>>>(
        samp, Wo_t, b_out, nullptr, attn_out, nullptr, M_Q, 256, 256);

    // 6. tgt = LN(pre_tgt + attn_out)
    add_ln_kernel<<<dim3(M_Q / 4), blk, 0, stream>>>(pre_tgt, attn_out, g1, be1, tgt);

    // 7. hidden = relu(tgt @ W1 + b1) (MFMA, f32 A, bf16 out)
    mfma_gemm_kernel<false, true, false, 1><<<dim3(4, M_Q / BM), blk, 0, stream>>>(
        tgt, W1_t, b1, nullptr, nullptr, hidden, M_Q, 512, 256);

    // 8. ff = hidden @ W2 + b2 (MFMA, bf16 A, K=512)
    mfma_gemm_kernel<true, false, false, 0><<<dim3(2, M_Q / BM), blk, 0, stream>>>(
        hidden, W2_t, b2, nullptr, ff, nullptr, M_Q, 256, 512);

    // 9. out = LN(tgt + ff)
    add_ln_kernel<<<dim3(M_Q / 4), blk, 0, stream>>>(tgt, ff, g3, be3, out);
}

// Round 4
// 413.374 us; speedup vs baseline: 1.9314x; 1.0125x over previous
//
#include <hip/hip_runtime.h>
#include <hip/hip_bf16.h>

// Problem constants (fixed by reference)
#define D_MODEL 256
#define NHEAD   8
#define NLEV    4
#define NPTS    4
#define HDIM    32
#define DFFN    512
#define NBATCH  8
#define LQ      1000
#define LIN     21760            // 128*128 + 64*64 + 32*32 + 16*16
#define M_VAL   (NBATCH * LIN)   // 174080
#define M_Q     (NBATCH * LQ)    // 8000

typedef __attribute__((ext_vector_type(8))) short short8;
typedef __attribute__((ext_vector_type(4))) short short4v;
typedef __attribute__((ext_vector_type(4))) float f32x4;

struct alignas(8) bf16x4 { __hip_bfloat16 a, b, c, d; };

__device__ __forceinline__ short f2bf(float f) {
    __hip_bfloat16 h = __float2bfloat16(f);
    return *reinterpret_cast<short*>(&h);
}
__device__ __forceinline__ float bf2f(short s) {
    return __uint_as_float(((unsigned)(unsigned short)s) << 16);
}

// ---------------------------------------------------------------------------
// Weight prep: transpose f32 [K][N] -> bf16 [N][K] for MFMA B-operand.
// ---------------------------------------------------------------------------
__global__ __launch_bounds__(256)
void transpose_weights_kernel(const float* __restrict__ Wv, const float* __restrict__ Wo,
                              const float* __restrict__ W1, const float* __restrict__ W2,
                              short* __restrict__ Wv_t, short* __restrict__ Wo_t,
                              short* __restrict__ W1_t, short* __restrict__ W2_t)
{
    const int b = blockIdx.x;
    const float* src; short* dst; int K, N, tb;
    if (b < 64)       { src = Wv; dst = Wv_t; K = 256; N = 256; tb = b; }
    else if (b < 128) { src = Wo; dst = Wo_t; K = 256; N = 256; tb = b - 64; }
    else if (b < 256) { src = W1; dst = W1_t; K = 256; N = 512; tb = b - 128; }
    else              { src = W2; dst = W2_t; K = 512; N = 256; tb = b - 256; }
    const int ntn = N >> 5;
    const int kt = tb / ntn, nt = tb % ntn;
    __shared__ float t[32][33];
    const int x = threadIdx.x & 31, y = threadIdx.x >> 5;
    #pragma unroll
    for (int j = 0; j < 4; ++j)
        t[y + 8*j][x] = src[(kt*32 + y + 8*j) * N + nt*32 + x];
    __syncthreads();
    #pragma unroll
    for (int j = 0; j < 4; ++j)
        dst[(nt*32 + y + 8*j) * K + kt*32 + x] = f2bf(t[x][y + 8*j]);
}

// ---------------------------------------------------------------------------
// bf16 MFMA GEMM, 2-phase pipelined, LANE-DENSE staging loads.
// Every wave-instruction covers contiguous memory (16 dense 64B lines/instr):
//   f32 A : instr i -> row (tid>>4)+16i, k-chunk (tid&15)*4  (16 lanes/row)
//   bf16 A: instr i -> row (tid>>3)+32i, k-chunk (tid&7)*8   (8 lanes/row)
//   B     : instr i -> row (tid>>3)+32i, k-chunk (tid&7)*8
// OMODE: 0 = f32 row-major, 1 = bf16 row-major, 2 = bf16 head-planes
//        (plane layout: addr = (col>>5)*M_VAL*32 + row*32 + (col&31))
// BM=64 BN=128 BK=64, 256 threads = 4 waves (2x2), wave tile 32x64.
// ---------------------------------------------------------------------------
#define BM 64
#define BN 128
#define BK 64

template<bool A_BF16, bool RELU, bool MASK, int OMODE>
__global__ __launch_bounds__(256)
void mfma_gemm_kernel(const void* __restrict__ Ain,
                      const short* __restrict__ Bt,
                      const float* __restrict__ bias,
                      const unsigned char* __restrict__ mask,
                      float* __restrict__ C, __hip_bfloat16* __restrict__ Cb,
                      int M, int N, int K)
{
    __shared__ short As[BM * BK];
    __shared__ short Bs[BN * BK];
    const int tid  = threadIdx.x;
    const int lane = tid & 63, wid = tid >> 6;
    const int wr = wid >> 1, wc = wid & 1;
    const long bm = (long)blockIdx.y * BM;
    const int  bn = blockIdx.x * BN;

    f32x4 acc[2][4];
    #pragma unroll
    for (int m = 0; m < 2; ++m)
        #pragma unroll
        for (int n = 0; n < 4; ++n)
            acc[m][n] = (f32x4){0.f, 0.f, 0.f, 0.f};

    // lane-dense staging coordinates
    const int arf = tid >> 4;          // f32 A row base (0..15), +16 per instr
    const int akf = (tid & 15) * 4;    // f32 A k-chunk (elems)
    const int arh = tid >> 3;          // bf16 A / B row base (0..31), +32 per instr
    const int akh = (tid & 7) * 8;     // bf16 k-chunk (elems)

    float4 a_f[4];
    short8 a_h[2];
    short8 b_r[4];

    auto load_tile = [&](int k0) {
        if (!A_BF16) {
            const float* Ap = (const float*)Ain + (long)(k0 + akf);
            #pragma unroll
            for (int i = 0; i < 4; ++i)
                a_f[i] = *reinterpret_cast<const float4*>(Ap + (bm + arf + 16*i) * (long)K);
        } else {
            const short* Ap = (const short*)Ain + (long)(k0 + akh);
            #pragma unroll
            for (int i = 0; i < 2; ++i)
                a_h[i] = *reinterpret_cast<const short8*>(Ap + (bm + arh + 32*i) * (long)K);
        }
        const short* Bp = Bt + (long)(k0 + akh);
        #pragma unroll
        for (int i = 0; i < 4; ++i)
            b_r[i] = *reinterpret_cast<const short8*>(Bp + (bn + arh + 32*i) * (long)K);
    };
    auto store_tile = [&]() {
        if (!A_BF16) {
            #pragma unroll
            for (int i = 0; i < 4; ++i) {
                const int r = arf + 16*i;
                short4v s;
                s[0] = f2bf(a_f[i].x); s[1] = f2bf(a_f[i].y);
                s[2] = f2bf(a_f[i].z); s[3] = f2bf(a_f[i].w);
                *reinterpret_cast<short4v*>(&As[r * BK + (akf ^ ((r & 7) << 3))]) = s;
            }
        } else {
            #pragma unroll
            for (int i = 0; i < 2; ++i) {
                const int r = arh + 32*i;
                *reinterpret_cast<short8*>(&As[r * BK + (akh ^ ((r & 7) << 3))]) = a_h[i];
            }
        }
        #pragma unroll
        for (int i = 0; i < 4; ++i) {
            const int r = arh + 32*i;
            *reinterpret_cast<short8*>(&Bs[r * BK + (akh ^ ((r & 7) << 3))]) = b_r[i];
        }
    };

    load_tile(0);
    const int nsteps = K / BK;
    for (int s = 0; s < nsteps; ++s) {
        store_tile();
        __syncthreads();
        if (s + 1 < nsteps) load_tile((s + 1) * BK);   // in flight during compute
        #pragma unroll
        for (int kk = 0; kk < 2; ++kk) {
            const int kb = kk * 32 + (lane >> 4) * 8;
            short8 af[2], bfr[4];
            #pragma unroll
            for (int m = 0; m < 2; ++m) {
                const int row = wr * 32 + m * 16 + (lane & 15);
                af[m] = *reinterpret_cast<const short8*>(&As[row * BK + (kb ^ ((row & 7) << 3))]);
            }
            #pragma unroll
            for (int n = 0; n < 4; ++n) {
                const int row = wc * 64 + n * 16 + (lane & 15);
                bfr[n] = *reinterpret_cast<const short8*>(&Bs[row * BK + (kb ^ ((row & 7) << 3))]);
            }
            #pragma unroll
            for (int m = 0; m < 2; ++m)
                #pragma unroll
                for (int n = 0; n < 4; ++n)
                    acc[m][n] = __builtin_amdgcn_mfma_f32_16x16x32_bf16(af[m], bfr[n], acc[m][n], 0, 0, 0);
        }
        __syncthreads();
    }

    // Epilogue. C/D layout: col = lane&15, row = (lane>>4)*4 + r
    #pragma unroll
    for (int m = 0; m < 2; ++m) {
        #pragma unroll
        for (int n = 0; n < 4; ++n) {
            const int col = bn + wc * 64 + n * 16 + (lane & 15);
            const float bc = bias[col];
            #pragma unroll
            for (int r = 0; r < 4; ++r) {
                const long row = bm + wr * 32 + m * 16 + (lane >> 4) * 4 + r;
                float v = acc[m][n][r] + bc;
                if (RELU) v = fmaxf(v, 0.f);
                if (MASK) { if (mask[row]) v = 0.f; }
                if (OMODE == 0)      C[row * (long)N + col] = v;
                else if (OMODE == 1) Cb[row * (long)N + col] = __float2bfloat16(v);
                else {  // head-plane bf16: [h][row][c]
                    Cb[(size_t)(col >> 5) * ((size_t)M_VAL * HDIM)
                       + (size_t)row * HDIM + (col & 31)] = __float2bfloat16(v);
                }
            }
        }
    }
}

// ---------------------------------------------------------------------------
// Fused off+attn projection, f32 SIMT (precision-sensitive), 2-phase prefetch.
// A = pre_tgt + pre_qpos [8000][256]. Grid (6,125): bn<256 -> off, else attn.
// (Staging loads here are already lane-dense: 4 lanes cover a row's 16-float
//  window contiguously.)
// ---------------------------------------------------------------------------
__global__ __launch_bounds__(256)
void proj_gemm_kernel(const float* __restrict__ A, const float* __restrict__ A2,
                      const float* __restrict__ Wo, const float* __restrict__ bo,
                      const float* __restrict__ Wa, const float* __restrict__ ba,
                      float* __restrict__ Co, float* __restrict__ Ca)
{
    __shared__ float As[16][68];
    __shared__ float Bs[16][64];
    const int tid = threadIdx.x;
    const long bm = (long)blockIdx.y * 64;
    const int  bn = blockIdx.x * 64;
    const float* B; const float* bias; float* C; int Nc, cb;
    if (bn < 256) { B = Wo; bias = bo; C = Co; Nc = 256; cb = bn; }
    else          { B = Wa; bias = ba; C = Ca; Nc = 128; cb = bn - 256; }

    const int tx = tid & 15, ty = tid >> 4;
    const int ar = tid >> 2, ac = (tid & 3) * 4;
    float acc[4][4] = {};
    const float* Aptr = A  + (bm + ar) * 256L + ac;
    const float* A2p  = A2 + (bm + ar) * 256L + ac;
    const float* Bptr = B + (long)ty * Nc + cb + tx * 4;

    float4 av, a2, bv;
    auto load = [&](int k0) {
        av = *reinterpret_cast<const float4*>(Aptr + k0);
        a2 = *reinterpret_cast<const float4*>(A2p + k0);
        bv = *reinterpret_cast<const float4*>(Bptr + (long)k0 * Nc);
    };
    load(0);
    for (int k0 = 0; k0 < 256; k0 += 16) {
        As[ac + 0][ar] = av.x + a2.x;
        As[ac + 1][ar] = av.y + a2.y;
        As[ac + 2][ar] = av.z + a2.z;
        As[ac + 3][ar] = av.w + a2.w;
        *reinterpret_cast<float4*>(&Bs[ty][tx * 4]) = bv;
        __syncthreads();
        if (k0 + 16 < 256) load(k0 + 16);
        #pragma unroll
        for (int kk = 0; kk < 16; ++kk) {
            float4 a4 = *reinterpret_cast<const float4*>(&As[kk][ty * 4]);
            float4 b4 = *reinterpret_cast<const float4*>(&Bs[kk][tx * 4]);
            float a[4] = {a4.x, a4.y, a4.z, a4.w};
            float b[4] = {b4.x, b4.y, b4.z, b4.w};
            #pragma unroll
            for (int i = 0; i < 4; ++i)
                #pragma unroll
                for (int j = 0; j < 4; ++j)
                    acc[i][j] = fmaf(a[i], b[j], acc[i][j]);
        }
        __syncthreads();
    }
    const float4 bias4 = *reinterpret_cast<const float4*>(bias + cb + tx * 4);
    #pragma unroll
    for (int i = 0; i < 4; ++i) {
        const long row = bm + ty * 4 + i;
        *reinterpret_cast<float4*>(C + row * Nc + cb + tx * 4) = make_float4(
            acc[i][0] + bias4.x, acc[i][1] + bias4.y,
            acc[i][2] + bias4.z, acc[i][3] + bias4.w);
    }
}

// ---------------------------------------------------------------------------
// Fused softmax + multi-scale deformable sampling, v3.
// Block = 1 query, 128 threads.
// Phase 1 (t = h*16 + lp): softmax + clamped tap-pair bases & weights -> LDS.
// Phase 2 (t = h*16 + cp): cp<8 accumulates x0-side, cp>=8 x1-side, 8B bf16x4
//   loads from head-plane value layout; single shfl_xor(8) combine at end.
// ---------------------------------------------------------------------------
__global__ __launch_bounds__(128)
void msdeform_sample_kernel(const float* __restrict__ off,
                            const float* __restrict__ logits,
                            const float* __restrict__ ref_pts,
                            const __hip_bfloat16* __restrict__ value,
                            __hip_bfloat16* __restrict__ samp)
{
    const int qi = blockIdx.x;
    const int n  = qi / LQ;
    const int t  = threadIdx.x;

    __shared__ int   s_base[128];
    __shared__ float s_wx[128][2];
    __shared__ float s_wy[128][2];

    {   // phase 1
        const int h = t >> 4, lp = t & 15, l = lp >> 2;
        const float lg = logits[qi * 128 + t];
        float mx = lg;
        #pragma unroll
        for (int m = 1; m < 16; m <<= 1) mx = fmaxf(mx, __shfl_xor(mx, m, 64));
        const float e = __expf(lg - mx);
        float ssum = e;
        #pragma unroll
        for (int m = 1; m < 16; m <<= 1) ssum += __shfl_xor(ssum, m, 64);
        const float w = e / ssum;

        const int Wl = 128 >> l;       // square levels: 128,64,32,16
        constexpr int Start[4] = {0, 16384, 20480, 21504};
        const float x = ref_pts[qi * 8 + l * 2 + 0] * (float)Wl - 0.5f
                      + off[qi * 256 + h * 32 + lp * 2 + 0];
        const float y = ref_pts[qi * 8 + l * 2 + 1] * (float)Wl - 0.5f
                      + off[qi * 256 + h * 32 + lp * 2 + 1];
        const float xf = floorf(x), yf = floorf(y);
        const float fx = x - xf, fy = y - yf;
        const int x0 = (int)xf, y0 = (int)yf;
        const int xb = min(max(x0, 0), Wl - 2);
        const int yb = min(max(y0, 0), Wl - 2);
        // weight of clamped position p: (p==x0)*(1-fx) + (p==x0+1)*fx
        const float wx0 = (xb == x0) ? (1.f - fx) : ((xb == x0 + 1) ? fx : 0.f);
        const float wx1 = (xb + 1 == x0) ? (1.f - fx) : ((xb == x0) ? fx : 0.f);
        const float wy0 = w * ((yb == y0) ? (1.f - fy) : ((yb == y0 + 1) ? fy : 0.f));
        const float wy1 = w * ((yb + 1 == y0) ? (1.f - fy) : ((yb == y0) ? fy : 0.f));

        const int row = n * LIN + Start[l] + yb * Wl + xb;
        s_base[t]  = (h * M_VAL + row) * HDIM;
        s_wx[t][0] = wx0; s_wx[t][1] = wx1;
        s_wy[t][0] = wy0; s_wy[t][1] = wy1;
    }
    __syncthreads();

    {   // phase 2
        const int h = t >> 4, cp = t & 15;
        const int side = cp >> 3, ch4 = (cp & 7) * 4;
        float a0 = 0.f, a1 = 0.f, a2 = 0.f, a3 = 0.f;
        #pragma unroll
        for (int lp = 0; lp < 16; ++lp) {
            const int i  = h * 16 + lp;
            const int rs = (128 >> (lp >> 2)) * HDIM;   // row stride (elems)
            const int b  = s_base[i] + side * HDIM + ch4;
            const float wxs = s_wx[i][side];
            const float w0 = wxs * s_wy[i][0];
            const float w1 = wxs * s_wy[i][1];
            const short4v v0 = *reinterpret_cast<const short4v*>(value + b);
            const short4v v1 = *reinterpret_cast<const short4v*>(value + b + rs);
            a0 += w0 * bf2f(v0[0]) + w1 * bf2f(v1[0]);
            a1 += w0 * bf2f(v0[1]) + w1 * bf2f(v1[1]);
            a2 += w0 * bf2f(v0[2]) + w1 * bf2f(v1[2]);
            a3 += w0 * bf2f(v0[3]) + w1 * bf2f(v1[3]);
        }
        // combine x0/x1 sides (linear): partner lane is t^8 (same wave)
        a0 += __shfl_xor(a0, 8, 64);
        a1 += __shfl_xor(a1, 8, 64);
        a2 += __shfl_xor(a2, 8, 64);
        a3 += __shfl_xor(a3, 8, 64);
        if (side == 0) {
            bf16x4 o { __float2bfloat16(a0), __float2bfloat16(a1),
                       __float2bfloat16(a2), __float2bfloat16(a3) };
            *reinterpret_cast<bf16x4*>(samp + (long)qi * D_MODEL + h * HDIM + ch4) = o;
        }
    }
}

// ---------------------------------------------------------------------------
// Fused residual-add + LayerNorm over D=256. One wave per row, 4 rows/block.
// ---------------------------------------------------------------------------
__global__ __launch_bounds__(256)
void add_ln_kernel(const float* __restrict__ x, const float* __restrict__ y,
                   const float* __restrict__ g, const float* __restrict__ b,
                   float* __restrict__ out)
{
    const int row  = blockIdx.x * 4 + (threadIdx.x >> 6);
    const int lane = threadIdx.x & 63;
    const long base = (long)row * D_MODEL + lane * 4;

    float4 xv = *reinterpret_cast<const float4*>(x + base);
    float4 yv = *reinterpret_cast<const float4*>(y + base);
    float4 v  = make_float4(xv.x + yv.x, xv.y + yv.y, xv.z + yv.z, xv.w + yv.w);

    float sum = v.x + v.y + v.z + v.w;
    float sq  = v.x * v.x + v.y * v.y + v.z * v.z + v.w * v.w;
    #pragma unroll
    for (int m = 1; m < 64; m <<= 1) {
        sum += __shfl_xor(sum, m, 64);
        sq  += __shfl_xor(sq,  m, 64);
    }
    const float mean = sum * (1.f / D_MODEL);
    const float var  = sq * (1.f / D_MODEL) - mean * mean;
    const float rstd = rsqrtf(var + 1e-5f);

    float4 gv = *reinterpret_cast<const float4*>(g + lane * 4);
    float4 bv = *reinterpret_cast<const float4*>(b + lane * 4);
    float4 o;
    o.x = (v.x - mean) * rstd * gv.x + bv.x;
    o.y = (v.y - mean) * rstd * gv.y + bv.y;
    o.z = (v.z - mean) * rstd * gv.z + bv.z;
    o.w = (v.w - mean) * rstd * gv.w + bv.w;
    *reinterpret_cast<float4*>(out + base) = o;
}

// ---------------------------------------------------------------------------
extern "C" void kernel_launch(void* const* d_in, const int* in_sizes, int n_in,
                              void* d_out, int out_size, void* d_ws, size_t ws_size,
                              hipStream_t stream)
{
    const float* pre_tgt  = (const float*)d_in[0];
    const float* pre_qpos = (const float*)d_in[1];
    const float* src      = (const float*)d_in[2];
    const float* ref_pts  = (const float*)d_in[3];
    const unsigned char* pad_mask = (const unsigned char*)d_in[4];
    const float* W_value = (const float*)d_in[7];
    const float* b_value = (const float*)d_in[8];
    const float* W_off   = (const float*)d_in[9];
    const float* b_off   = (const float*)d_in[10];
    const float* W_attn  = (const float*)d_in[11];
    const float* b_attn  = (const float*)d_in[12];
    const float* W_out   = (const float*)d_in[13];
    const float* b_out   = (const float*)d_in[14];
    const float* g1      = (const float*)d_in[15];
    const float* be1     = (const float*)d_in[16];
    const float* W1      = (const float*)d_in[17];
    const float* b1      = (const float*)d_in[18];
    const float* W2      = (const float*)d_in[19];
    const float* b2      = (const float*)d_in[20];
    const float* g3      = (const float*)d_in[21];
    const float* be3     = (const float*)d_in[22];
    float* out = (float*)d_out;

    // Workspace layout
    char* w = (char*)d_ws;
    size_t o = 0;
    __hip_bfloat16* value = (__hip_bfloat16*)(w + o); o += (size_t)M_VAL * D_MODEL * 2;   // 89.1 MB (head planes)
    float* offb    = (float*)(w + o); o += (size_t)M_Q * 256 * 4;
    float* logits  = (float*)(w + o); o += (size_t)M_Q * 128 * 4;
    __hip_bfloat16* samp = (__hip_bfloat16*)(w + o); o += (size_t)M_Q * 256 * 2;
    float* tgt     = (float*)(w + o); o += (size_t)M_Q * 256 * 4;
    short* Wv_t    = (short*)(w + o); o += 256 * 256 * 2;
    short* Wo_t    = (short*)(w + o); o += 256 * 256 * 2;
    short* W1_t    = (short*)(w + o); o += 512 * 256 * 2;
    short* W2_t    = (short*)(w + o); o += 256 * 512 * 2;
    // Aliases into the (dead) value region:
    float* attn_out = (float*)w;                               // 8 MB
    __hip_bfloat16* hidden = (__hip_bfloat16*)(w + 20000000);  // 8.2 MB bf16 [8000][512]
    float* ff = offb;                                          // offb dead after sampling

    const dim3 blk(256);

    // 0. prep: weights -> bf16 transposed [N][K]
    transpose_weights_kernel<<<dim3(384), blk, 0, stream>>>(
        W_value, W_out, W1, W2, Wv_t, Wo_t, W1_t, W2_t);

    // 1. value = src @ W_value + b_value, masked, bf16 head-plane out (MFMA)
    mfma_gemm_kernel<false, false, true, 2><<<dim3(2, M_VAL / BM), blk, 0, stream>>>(
        src, Wv_t, b_value, pad_mask, nullptr, value, M_VAL, 256, 256);

    // 2+3. fused off/attn projections (f32)
    proj_gemm_kernel<<<dim3(6, M_Q / 64), blk, 0, stream>>>(
        pre_tgt, pre_qpos, W_off, b_off, W_attn, b_attn, offb, logits);

    // 4. fused softmax + bilinear sampling -> samp bf16
    msdeform_sample_kernel<<<dim3(M_Q), dim3(128), 0, stream>>>(
        offb, logits, ref_pts, value, samp);

    // 5. attn_out = samp @ W_out + b_out (MFMA, bf16 A)
    mfma_gemm_kernel<true, false, false, 0><<<dim3(2, M_Q / BM), blk, 0, stream>>>(
        samp, Wo_t, b_out, nullptr, attn_out, nullptr, M_Q, 256, 256);

    // 6. tgt = LN(pre_tgt + attn_out)
    add_ln_kernel<<<dim3(M_Q / 4), blk, 0, stream>>>(pre_tgt, attn_out, g1, be1, tgt);

    // 7. hidden = relu(tgt @ W1 + b1) (MFMA, f32 A, bf16 out)
    mfma_gemm_kernel<false, true, false, 1><<<dim3(4, M_Q / BM), blk, 0, stream>>>(
        tgt, W1_t, b1, nullptr, nullptr, hidden, M_Q, 512, 256);

    // 8. ff = hidden @ W2 + b2 (MFMA, bf16 A, K=512)
    mfma_gemm_kernel<true, false, false, 0><<<dim3(2, M_Q / BM), blk, 0, stream>>>(
        hidden, W2_t, b2, nullptr, ff, nullptr, M_Q, 256, 512);

    // 9. out = LN(tgt + ff)
    add_ln_kernel<<<dim3(M_Q / 4), blk, 0, stream>>>(tgt, ff, g3, be3, out);
}